// Round 2
// baseline (414.957 us; speedup 1.0000x reference)
//
#include <hip/hip_runtime.h>

// DYDConv2d: dynamic per-pixel depthwise 3x3 conv, stride 1, pad 1.
// input  [B=8, C=64, H=128, W=128] fp32
// weight [B, C, 3, 3, outH=128, outW=128] fp32
// output [B, C, 128, 128] fp32
//
// Memory-bound: weight tensor (302 MB) is single-use. Strategy: stream it
// with fully-coalesced float4 loads (one thread = 4 consecutive ow).
// Roofline: ~369 MB min traffic / 6.3 TB/s ≈ 59 us.

namespace {
constexpr int kB = 8;
constexpr int kC = 64;
constexpr int kH = 128;
constexpr int kW = 128;
constexpr int kPlane = kH * kW;          // 16384
constexpr int kThreadsTotal = kB * kC * kH * (kW / 4);  // 2,097,152
}

__global__ __launch_bounds__(256) void dyd_conv_kernel(
    const float* __restrict__ in,
    const float* __restrict__ wgt,
    float* __restrict__ out) {
    int idx = blockIdx.x * blockDim.x + threadIdx.x;
    // lane layout: 32 threads per row (4 cols each), rows contiguous.
    int ow0 = (idx & 31) << 2;        // 0,4,...,124 (16B-aligned column)
    int oh  = (idx >> 5) & 127;
    int bc  = idx >> 12;              // b*C + c, 0..511

    const float* inp = in + (size_t)bc * kPlane;
    const float* wp  = wgt + (size_t)bc * 9 * kPlane + oh * kW + ow0;

    float acc0 = 0.f, acc1 = 0.f, acc2 = 0.f, acc3 = 0.f;

#pragma unroll
    for (int i = 0; i < 3; ++i) {
        int ih = oh + i - 1;
        float c0, c1, c2, c3, c4, c5;   // input cols ow0-1 .. ow0+4
        if (ih >= 0 && ih < kH) {
            const float* row = inp + ih * kW;
            float4 mid = *(const float4*)(row + ow0);   // aligned
            c1 = mid.x; c2 = mid.y; c3 = mid.z; c4 = mid.w;
            c0 = (ow0 > 0)        ? row[ow0 - 1] : 0.f;
            c5 = (ow0 + 4 < kW)   ? row[ow0 + 4] : 0.f;
        } else {
            c0 = c1 = c2 = c3 = c4 = c5 = 0.f;
        }
#pragma unroll
        for (int j = 0; j < 3; ++j) {
            float4 w4 = *(const float4*)(wp + (i * 3 + j) * kPlane);
            float iv0, iv1, iv2, iv3;
            if (j == 0)      { iv0 = c0; iv1 = c1; iv2 = c2; iv3 = c3; }
            else if (j == 1) { iv0 = c1; iv1 = c2; iv2 = c3; iv3 = c4; }
            else             { iv0 = c2; iv1 = c3; iv2 = c4; iv3 = c5; }
            acc0 += w4.x * iv0;
            acc1 += w4.y * iv1;
            acc2 += w4.z * iv2;
            acc3 += w4.w * iv3;
        }
    }

    float4 o;
    o.x = acc0; o.y = acc1; o.z = acc2; o.w = acc3;
    *(float4*)(out + (size_t)bc * kPlane + oh * kW + ow0) = o;
}

extern "C" void kernel_launch(void* const* d_in, const int* in_sizes, int n_in,
                              void* d_out, int out_size, void* d_ws, size_t ws_size,
                              hipStream_t stream) {
    const float* in  = (const float*)d_in[0];
    const float* wgt = (const float*)d_in[1];
    float* out = (float*)d_out;
    constexpr int kBlock = 256;
    constexpr int kGrid = kThreadsTotal / kBlock;   // 8192
    dyd_conv_kernel<<<kGrid, kBlock, 0, stream>>>(in, wgt, out);
}

// Round 4
// 399.789 us; speedup vs baseline: 1.0379x; 1.0379x over previous
//
#include <hip/hip_runtime.h>

// DYDConv2d: dynamic per-pixel depthwise 3x3 conv, stride 1, pad 1.
// input  [B=8, C=64, H=128, W=128] fp32
// weight [B, C, 3, 3, outH=128, outW=128] fp32   (302 MB, single-use)
// output [B, C, 128, 128] fp32
//
// Memory-bound: min traffic ~369 MB -> ~59 us at 6.3 TB/s.
// R2 evidence: kernel < 181 us (absent from top-5), wall 415 us includes
// ~300 us of harness resets (1.2 GB ws poison @182 us + input restore).
// This round: halo via __shfl (19->13 vmem inst/thread), nontemporal
// weight loads + output store (single-use; keep L2 for input planes).
// R3 fix: nontemporal builtins need a clang ext_vector_type, not HIP float4.

typedef float vfloat4 __attribute__((ext_vector_type(4)));

namespace {
constexpr int kH = 128;
constexpr int kW = 128;
constexpr int kPlane = kH * kW;                          // 16384
constexpr int kThreadsTotal = 8 * 64 * kH * (kW / 4);    // 2,097,152
}

__global__ __launch_bounds__(256) void dyd_conv_kernel(
    const float* __restrict__ in,
    const float* __restrict__ wgt,
    float* __restrict__ out) {
    int idx = blockIdx.x * blockDim.x + threadIdx.x;
    int lane = threadIdx.x & 63;
    // lane layout: 32 threads per output row (4 cols each), rows contiguous,
    // so every vector op is a fully-coalesced 1 KB wave transaction.
    int ow0 = (idx & 31) << 2;        // 0,4,...,124 (16B-aligned)
    int oh  = (idx >> 5) & 127;
    int bc  = idx >> 12;              // b*C + c

    const float* inp = in + (size_t)bc * kPlane;
    const float* wp  = wgt + (size_t)bc * (9 * kPlane) + oh * kW + ow0;

    float acc0 = 0.f, acc1 = 0.f, acc2 = 0.f, acc3 = 0.f;

#pragma unroll
    for (int i = 0; i < 3; ++i) {
        int ih = oh + i - 1;
        vfloat4 mid = {0.f, 0.f, 0.f, 0.f};
        if (ih >= 0 && ih < kH)
            mid = *(const vfloat4*)(inp + ih * kW + ow0);

        // Halo columns from neighbor lanes. Lanes whose pull crosses a row
        // edge are exactly the pad lanes -> masked to 0.
        float c0 = __shfl(mid.w, lane - 1);   // col ow0-1
        float c5 = __shfl(mid.x, lane + 1);   // col ow0+4
        if (ow0 == 0)        c0 = 0.f;
        if (ow0 + 4 >= kW)   c5 = 0.f;

        // Single-use weights: nontemporal to avoid polluting L2.
        vfloat4 w0 = __builtin_nontemporal_load((const vfloat4*)(wp + (i * 3 + 0) * kPlane));
        vfloat4 w1 = __builtin_nontemporal_load((const vfloat4*)(wp + (i * 3 + 1) * kPlane));
        vfloat4 w2 = __builtin_nontemporal_load((const vfloat4*)(wp + (i * 3 + 2) * kPlane));

        acc0 += w0.x * c0    + w1.x * mid.x + w2.x * mid.y;
        acc1 += w0.y * mid.x + w1.y * mid.y + w2.y * mid.z;
        acc2 += w0.z * mid.y + w1.z * mid.z + w2.z * mid.w;
        acc3 += w0.w * mid.z + w1.w * mid.w + w2.w * c5;
    }

    vfloat4 o = {acc0, acc1, acc2, acc3};
    __builtin_nontemporal_store(o, (vfloat4*)(out + (size_t)bc * kPlane + oh * kW + ow0));
}

extern "C" void kernel_launch(void* const* d_in, const int* in_sizes, int n_in,
                              void* d_out, int out_size, void* d_ws, size_t ws_size,
                              hipStream_t stream) {
    const float* in  = (const float*)d_in[0];
    const float* wgt = (const float*)d_in[1];
    float* out = (float*)d_out;
    constexpr int kBlock = 256;
    constexpr int kGrid = kThreadsTotal / kBlock;   // 8192
    dyd_conv_kernel<<<kGrid, kBlock, 0, stream>>>(in, wgt, out);
}